// Round 6
// baseline (103.695 us; speedup 1.0000x reference)
//
#include <hip/hip_runtime.h>

#define CUTOFF 5.0f
#define FSQRT(x) __builtin_amdgcn_sqrtf(x)

// ws float layout (every slot written unconditionally every launch):
//  [0, 1024)     lig_part[512][2]  (num, den) per ligand block (triangular: half of ref sums)
//  [1024, 1088)  lig_coord[64]     per-batch coord ratio (t==0 blocks)
//  [1088, 3136)  sc_part[512][4]   (mse, am, val, has) per sidechain block

#define NSC_BLK 512   // blocks [0,512): sidechain, 128 residues each, triangular split across halves
#define NLIG_BLK 512  // blocks [512,1024): ligand, 64 batches * 8 balanced tile-pairs
#define GRID (NSC_BLK + NLIG_BLK)

// one pair evaluation: dist(tgt_i, tgt_j) vs dist(pred_i, pred_j), weight w
// NOTE: no fmax(.,eps) / tsq>0 guards: every evaluated pair with nonzero w is
// between distinct atoms (triangular gating / mask-folded coords), so tsq>0
// holds for all contributing pairs and sqrt(0)=0 is benign for the rest.
#define PAIR_EVAL(ti, pi, tjx, tjy, tjz, pjx, pjy, pjz, w, numv, denv)    \
  {                                                                       \
    float dx = (ti).x - (tjx), dy = (ti).y - (tjy), dz = (ti).z - (tjz);  \
    float tsq = dx * dx + dy * dy + dz * dz;                              \
    float td = FSQRT(tsq);                                                \
    float ww = (w);                                                       \
    ww = (td <= CUTOFF) ? ww : 0.f;                                       \
    float qx = (pi).x - (pjx), qy = (pi).y - (pjy), qz = (pi).z - (pjz);  \
    float pd = FSQRT(qx * qx + qy * qy + qz * qz);                        \
    float dd = pd - td;                                                   \
    numv += (ww * dd) * dd;                                               \
    denv += ww;                                                           \
  }

// __launch_bounds__(256, 4): 4 waves/EU = 4 blocks/CU -> all 1024 blocks
// co-resident in one dispatch wave (caps VGPR at 128).
__global__ __launch_bounds__(256, 4) void fused_kernel(
    const float* __restrict__ lig_pred, const float* __restrict__ lig_tgt,
    const int* __restrict__ lig_mask,
    const float* __restrict__ sc_pred, const float* __restrict__ sc_tgt,
    const int* __restrict__ sc_mask,
    float* __restrict__ ws) {
  const int tid = threadIdx.x;
  __shared__ float4 stage4[128];  // 2 KB; ligand tiles only (sc path is direct-load)
  __shared__ float red[4][4];
  __shared__ float2 scpart[128];  // sc cross-half (num,den) combine

  if (blockIdx.x < NSC_BLK) {
    // ===== sidechain: 128 residues/block, direct global loads (no LDS staging) =====
    // half 0 (waves 0-1): j = 1..9   (45 pairs)   + mse/am
    // half 1 (waves 2-3): j = 10..13 (46 pairs)
    // Lane r and lane 128+r read the same residue (2nd read L1/L2-hits).
    // Per-lane 21 x float2: 168 B lane stride -> every byte of every touched
    // cache line is used; the 21 loads revisit the same lines (L1-resident).
    const int sb = blockIdx.x;
    const int r = tid & 127;   // residue within block
    const int half = tid >> 7; // which j-range this lane evaluates (wave-uniform)
    float P[42], T[42];        // pred / tgt coords (T gets mask folded in after mse)

    const float2* p2 = (const float2*)(sc_pred + ((size_t)sb * 128 + r) * 42);
    const float2* t2 = (const float2*)(sc_tgt + ((size_t)sb * 128 + r) * 42);
#pragma unroll
    for (int k = 0; k < 21; k++) {
      float2 v = p2[k]; P[2 * k] = v.x; P[2 * k + 1] = v.y;
      float2 u = t2[k]; T[2 * k] = u.x; T[2 * k + 1] = u.y;
    }

    // masks: 14 ints per residue, 8B-aligned -> int2 x7 (both halves read, cached)
    const int2* mp2 = (const int2*)(sc_mask + ((size_t)sb * 128 + r) * 14);
    float m[14];
#pragma unroll
    for (int k = 0; k < 7; k++) {
      int2 v = mp2[k];
      m[2 * k] = (v.x != 0) ? 1.f : 0.f;
      m[2 * k + 1] = (v.y != 0) ? 1.f : 0.f;
    }

    float mse = 0.f, am = 0.f;
    if (half == 0) {  // wave-uniform: half 1 never contributes mse/am
#pragma unroll
      for (int a = 0; a < 14; a++) {
        float dx = P[3 * a] - T[3 * a], dy = P[3 * a + 1] - T[3 * a + 1],
              dz = P[3 * a + 2] - T[3 * a + 2];
        mse += m[a] * ((dx * dx + dy * dy + dz * dz) * (1.f / 3.f));
        am += m[a];
      }
    }
#pragma unroll
    for (int a = 0; a < 14; a++) {
      // fold mask into tgt coords: masked atoms pushed far apart (distinct per
      // atom so masked-masked pairs are also far) -> td > CUTOFF -> w = 0
      T[3 * a] += (1.f - m[a]) * (30000.f * (float)(a + 1));
    }

    // triangular pair sum; reference's ordered sum = 2x this (diag has tsq==0)
    float num = 0.f, den = 0.f;
    if (half == 0) {
#pragma unroll
      for (int j = 1; j <= 9; j++) {
#pragma unroll
        for (int i = 0; i < j; i++) {
          float dx = T[3 * i] - T[3 * j], dy = T[3 * i + 1] - T[3 * j + 1],
                dz = T[3 * i + 2] - T[3 * j + 2];
          float td = FSQRT(dx * dx + dy * dy + dz * dz);
          float w = (td <= CUTOFF) ? 1.f : 0.f;
          float qx = P[3 * i] - P[3 * j], qy = P[3 * i + 1] - P[3 * j + 1],
                qz = P[3 * i + 2] - P[3 * j + 2];
          float pd = FSQRT(qx * qx + qy * qy + qz * qz);
          float d = pd - td;
          num += (w * d) * d;
          den += w;
        }
      }
    } else {
#pragma unroll
      for (int j = 10; j <= 13; j++) {
#pragma unroll
        for (int i = 0; i < j; i++) {
          float dx = T[3 * i] - T[3 * j], dy = T[3 * i + 1] - T[3 * j + 1],
                dz = T[3 * i + 2] - T[3 * j + 2];
          float td = FSQRT(dx * dx + dy * dy + dz * dz);
          float w = (td <= CUTOFF) ? 1.f : 0.f;
          float qx = P[3 * i] - P[3 * j], qy = P[3 * i + 1] - P[3 * j + 1],
                qz = P[3 * i + 2] - P[3 * j + 2];
          float pd = FSQRT(qx * qx + qy * qy + qz * qz);
          float d = pd - td;
          num += (w * d) * d;
          den += w;
        }
      }
    }

    // combine halves per residue, then nonlinear group step (half 0 owns it)
    if (half == 1) scpart[r] = make_float2(num, den);
    __syncthreads();
    float val = 0.f, has = 0.f;
    if (half == 0) {
      float2 o = scpart[r];
      float ng = num + o.x, dg = den + o.y;
      val = (dg > 0.f) ? (ng + ng) / fmaxf(dg + dg, 1.f) : 0.f;
      has = (dg > 0.f) ? 1.f : 0.f;
    }

    for (int off = 32; off > 0; off >>= 1) {
      mse += __shfl_down(mse, off, 64);
      am += __shfl_down(am, off, 64);
      val += __shfl_down(val, off, 64);
      has += __shfl_down(has, off, 64);
    }
    int lane = tid & 63, wv = tid >> 6;
    if (lane == 0) { red[0][wv] = mse; red[1][wv] = am; red[2][wv] = val; red[3][wv] = has; }
    __syncthreads();
    if (tid == 0) {
      float* p = ws + 1088 + (size_t)sb * 4;
      p[0] = red[0][0] + red[0][1] + red[0][2] + red[0][3];
      p[1] = red[1][0] + red[1][1] + red[1][2] + red[1][3];
      p[2] = red[2][0] + red[2][1] + red[2][2] + red[2][3];
      p[3] = red[3][0] + red[3][1] + red[3][2] + red[3][3];
    }
  } else {
    // ====== ligand: triangular, balanced tile-pairs {t,15-t}, 3 fused j-slots ======
    // Slot A0: j = i0a+tid          (always valid; gate j>i <=> tid>ii)
    // Slot A1: j = i0a+256+tid      (valid iff j<512; triangular gate always true)
    // Slot B : j = i0b+tid          (valid iff j<512; gate tid>ii)
    // Same covered pair set as R7 (verified); invalid slots predicated w=0.
    const int L = 512;
    const int lb = blockIdx.x - NSC_BLK;  // 0..511
    const int b = lb >> 3;
    const int t = lb & 7;
    const int i0a = 32 * t;
    const int i0b = 32 * (15 - t);
    const float* pb = lig_pred + (size_t)b * L * 3;
    const float* tb = lig_tgt + (size_t)b * L * 3;
    const int* mb = lig_mask + (size_t)b * L;

    float4* st4 = stage4;       // [0,32): tileA tgt(+mask), [32,64): tileB tgt(+mask)
    float4* sp4 = stage4 + 64;  // [0,32): tileA pred,       [32,64): tileB pred

    if (tid < 128) {
      int which = tid >> 5;  // 0: A-tgt, 1: B-tgt, 2: A-pred, 3: B-pred
      int idx = tid & 31;
      int i = ((which & 1) ? i0b : i0a) + idx;
      if (which < 2) {
        st4[(which << 5) + idx] =
            make_float4(tb[3 * i], tb[3 * i + 1], tb[3 * i + 2], (mb[i] != 0) ? 1.f : 0.f);
      } else {
        sp4[((which & 1) << 5) + idx] =
            make_float4(pb[3 * i], pb[3 * i + 1], pb[3 * i + 2], 0.f);
      }
    }

    // j-point loads (overlap with staging; barrier below covers both)
    const int jA0 = i0a + tid;
    const int jA1r = i0a + 256 + tid;
    const int jA1 = jA1r & (L - 1);  // clamp into bounds; weight zeroed if invalid
    const int jBr = i0b + tid;
    const int jB = jBr & (L - 1);

    float pA0x = pb[3 * jA0], pA0y = pb[3 * jA0 + 1], pA0z = pb[3 * jA0 + 2];
    float tA0x = tb[3 * jA0], tA0y = tb[3 * jA0 + 1], tA0z = tb[3 * jA0 + 2];
    float mA0 = (mb[jA0] != 0) ? 1.f : 0.f;
    float pA1x = pb[3 * jA1], pA1y = pb[3 * jA1 + 1], pA1z = pb[3 * jA1 + 2];
    float tA1x = tb[3 * jA1], tA1y = tb[3 * jA1 + 1], tA1z = tb[3 * jA1 + 2];
    float mA1 = (jA1r < L && mb[jA1] != 0) ? 1.f : 0.f;
    float pBx = pb[3 * jB], pBy = pb[3 * jB + 1], pBz = pb[3 * jB + 2];
    float tBx = tb[3 * jB], tBy = tb[3 * jB + 1], tBz = tb[3 * jB + 2];
    float mB = (jBr < L && mb[jB] != 0) ? 1.f : 0.f;

    float se = 0.f, cnt = 0.f;
    if (t == 0) {  // A0 (j=tid) + A1 (j=256+tid, all valid at t==0) cover all 512 atoms
      float dx = pA0x - tA0x, dy = pA0y - tA0y, dz = pA0z - tA0z;
      se += mA0 * (dx * dx + dy * dy + dz * dz);
      cnt += mA0;
      dx = pA1x - tA1x; dy = pA1y - tA1y; dz = pA1z - tA1z;
      se += mA1 * (dx * dx + dy * dy + dz * dz);
      cnt += mA1;
    }
    __syncthreads();

    // num,den accumulate exactly HALF of the reference's symmetric sums.
    float nA0 = 0.f, dA0 = 0.f, nA1 = 0.f, dA1 = 0.f, nB = 0.f, dB = 0.f;
#pragma unroll 8
    for (int ii = 0; ii < 32; ii++) {
      float4 tiA = st4[ii];  // wave-uniform -> broadcast ds_read_b128
      float4 piA = sp4[ii];
      float4 tiB = st4[32 + ii];
      float4 piB = sp4[32 + ii];
      float wA0 = (tid > ii) ? tiA.w * mA0 : 0.f;
      PAIR_EVAL(tiA, piA, tA0x, tA0y, tA0z, pA0x, pA0y, pA0z, wA0, nA0, dA0);
      float wA1 = tiA.w * mA1;  // triangular gate provably true for this slot
      PAIR_EVAL(tiA, piA, tA1x, tA1y, tA1z, pA1x, pA1y, pA1z, wA1, nA1, dA1);
      float wB = (tid > ii) ? tiB.w * mB : 0.f;
      PAIR_EVAL(tiB, piB, tBx, tBy, tBz, pBx, pBy, pBz, wB, nB, dB);
    }

    float num = nA0 + nA1 + nB, den = dA0 + dA1 + dB;
    for (int off = 32; off > 0; off >>= 1) {
      num += __shfl_down(num, off, 64);
      den += __shfl_down(den, off, 64);
      se += __shfl_down(se, off, 64);
      cnt += __shfl_down(cnt, off, 64);
    }
    int lane = tid & 63, wv = tid >> 6;
    if (lane == 0) { red[0][wv] = num; red[1][wv] = den; red[2][wv] = se; red[3][wv] = cnt; }
    __syncthreads();
    if (tid == 0) {
      ws[lb * 2 + 0] = red[0][0] + red[0][1] + red[0][2] + red[0][3];
      ws[lb * 2 + 1] = red[1][0] + red[1][1] + red[1][2] + red[1][3];
      if (t == 0) {
        float se_t = red[2][0] + red[2][1] + red[2][2] + red[2][3];
        float cnt_t = red[3][0] + red[3][1] + red[3][2] + red[3][3];
        ws[1024 + b] = se_t / (3.f * fmaxf(cnt_t, 1.f));
      }
    }
  }
}

__global__ __launch_bounds__(256) void finalize_kernel(const float* __restrict__ ws,
                                                       float* __restrict__ out) {
  const int tid = threadIdx.x;
  __shared__ float sred[4][4];

  const float* sc = ws + 1088;
  float s0 = 0.f, s1 = 0.f, s2 = 0.f, s3 = 0.f;
  for (int i = tid; i < 512; i += 256) {
    s0 += sc[4 * i + 0]; s1 += sc[4 * i + 1]; s2 += sc[4 * i + 2]; s3 += sc[4 * i + 3];
  }
  for (int off = 32; off > 0; off >>= 1) {
    s0 += __shfl_down(s0, off, 64);
    s1 += __shfl_down(s1, off, 64);
    s2 += __shfl_down(s2, off, 64);
    s3 += __shfl_down(s3, off, 64);
  }
  int lane = tid & 63, wv = tid >> 6;
  if (lane == 0) { sred[0][wv] = s0; sred[1][wv] = s1; sred[2][wv] = s2; sred[3][wv] = s3; }
  __syncthreads();

  float lval = 0.f, lhas = 0.f, lcoord = 0.f;
  if (tid < 64) {
    float n = 0.f, d = 0.f;
    for (int t = 0; t < 8; t++) {
      n += ws[(tid * 8 + t) * 2 + 0];
      d += ws[(tid * 8 + t) * 2 + 1];
    }
    lval = (d > 0.f) ? n / fmaxf(d, 1.f) : 0.f;
    lhas = (d > 0.f) ? 1.f : 0.f;
    lcoord = ws[1024 + tid];
    for (int off = 32; off > 0; off >>= 1) {
      lval += __shfl_down(lval, off, 64);
      lhas += __shfl_down(lhas, off, 64);
      lcoord += __shfl_down(lcoord, off, 64);
    }
  }
  if (tid == 0) {
    float sc_mse = sred[0][0] + sred[0][1] + sred[0][2] + sred[0][3];
    float sc_am = sred[1][0] + sred[1][1] + sred[1][2] + sred[1][3];
    float sc_val = sred[2][0] + sred[2][1] + sred[2][2] + sred[2][3];
    float sc_has = sred[3][0] + sred[3][1] + sred[3][2] + sred[3][3];
    float ligand_loss = lcoord * (1.f / 64.f);
    float ligand_dist_loss = lval / fmaxf(lhas, 1.f);
    float sidechain_loss = sc_mse / fmaxf(sc_am, 1.f);
    float sidechain_dist_loss = sc_val / fmaxf(sc_has, 1.f);
    out[0] = ligand_loss + 0.2f * ligand_dist_loss + 0.5f * sidechain_loss +
             0.1f * sidechain_dist_loss;
  }
}

extern "C" void kernel_launch(void* const* d_in, const int* in_sizes, int n_in,
                              void* d_out, int out_size, void* d_ws, size_t ws_size,
                              hipStream_t stream) {
  const float* ligand_pred = (const float*)d_in[0];
  const float* ligand_tgt = (const float*)d_in[1];
  const float* sidechain_pred = (const float*)d_in[2];
  const float* sidechain_tgt = (const float*)d_in[3];
  const int* ligand_mask = (const int*)d_in[4];
  const int* atom_mask = (const int*)d_in[5];
  float* out = (float*)d_out;
  float* ws = (float*)d_ws;

  fused_kernel<<<GRID, 256, 0, stream>>>(ligand_pred, ligand_tgt, ligand_mask,
                                         sidechain_pred, sidechain_tgt, atom_mask, ws);
  finalize_kernel<<<1, 256, 0, stream>>>(ws, out);
}

// Round 7
// 98.074 us; speedup vs baseline: 1.0573x; 1.0573x over previous
//
#include <hip/hip_runtime.h>

#define CUTOFF 5.0f
#define FSQRT(x) __builtin_amdgcn_sqrtf(x)

// ws float layout (every slot written unconditionally every launch):
//  [0, 1024)     lig_part[512][2]  (num, den) per ligand block (triangular: half of ref sums)
//  [1024, 1088)  lig_coord[64]     per-batch coord ratio (t==0 blocks)
//  [1088, 3136)  sc_part[512][4]   (mse, am, val, has) per sidechain block

#define NSC_BLK 512   // blocks [0,512): sidechain, 128 residues each, triangular split across halves
#define NLIG_BLK 512  // blocks [512,1024): ligand, 64 batches * 8 balanced tile-pairs
#define GRID (NSC_BLK + NLIG_BLK)

// one pair evaluation: dist(tgt_i, tgt_j) vs dist(pred_i, pred_j), weight w
// NOTE: no fmax(.,eps) / tsq>0 guards: every evaluated pair with nonzero w is
// between distinct atoms (triangular gating / mask-folded coords), so tsq>0
// holds for all contributing pairs and sqrt(0)=0 is benign for the rest.
#define PAIR_EVAL(ti, pi, tjx, tjy, tjz, pjx, pjy, pjz, w, numv, denv)    \
  {                                                                       \
    float dx = (ti).x - (tjx), dy = (ti).y - (tjy), dz = (ti).z - (tjz);  \
    float tsq = dx * dx + dy * dy + dz * dz;                              \
    float td = FSQRT(tsq);                                                \
    float ww = (w);                                                       \
    ww = (td <= CUTOFF) ? ww : 0.f;                                       \
    float qx = (pi).x - (pjx), qy = (pi).y - (pjy), qz = (pi).z - (pjz);  \
    float pd = FSQRT(qx * qx + qy * qy + qz * qz);                        \
    float dd = pd - td;                                                   \
    numv += (ww * dd) * dd;                                               \
    denv += ww;                                                           \
  }

// __launch_bounds__(256, 4): 4 waves/EU = 4 blocks/CU -> all 1024 blocks
// co-resident in one dispatch wave (caps VGPR at 128; sc path needs ~110).
// LDS staging (NOT direct loads) for sc: direct per-lane 168B-slab gathers
// thrash L1 (84KB live/CU vs 32KB L1) — measured +3-4us regression in R6.
__global__ __launch_bounds__(256, 4) void fused_kernel(
    const float* __restrict__ lig_pred, const float* __restrict__ lig_tgt,
    const int* __restrict__ lig_mask,
    const float* __restrict__ sc_pred, const float* __restrict__ sc_tgt,
    const int* __restrict__ sc_mask,
    float* __restrict__ ws) {
  const int tid = threadIdx.x;
  __shared__ float4 stage4[1344];  // 21.5 KB; sc staging / ligand tiles (aliased)
  __shared__ float red[4][4];
  __shared__ float2 scpart[128];   // sc cross-half (num,den) combine

  if (blockIdx.x < NSC_BLK) {
    // ===== sidechain: 128 residues/block, triangular 91 pairs split across halves =====
    // half 0 (waves 0-1): j = 1..9   (45 pairs)   + mse/am
    // half 1 (waves 2-3): j = 10..13 (46 pairs)
    // Wave-uniform split -> no divergence; combine per-residue via scpart LDS.
    const int sb = blockIdx.x;
    const int r = tid & 127;   // residue within block
    const int half = tid >> 7; // which j-range this lane evaluates (wave-uniform)
    float ax[14], ay[14], az[14];  // pred
    float bx[14], by[14], bz[14];  // tgt (mask folded in after mse)

    const float4* srcp = (const float4*)(sc_pred + (size_t)sb * 5376);
    for (int k = tid; k < 1344; k += 256) stage4[k] = srcp[k];
    __syncthreads();
    {
      const float* s = ((const float*)stage4) + r * 42;
#pragma unroll
      for (int a = 0; a < 14; a++) {
        ax[a] = s[3 * a]; ay[a] = s[3 * a + 1]; az[a] = s[3 * a + 2];
      }
    }
    __syncthreads();
    const float4* srct = (const float4*)(sc_tgt + (size_t)sb * 5376);
    for (int k = tid; k < 1344; k += 256) stage4[k] = srct[k];
    __syncthreads();
    {
      const float* s = ((const float*)stage4) + r * 42;
#pragma unroll
      for (int a = 0; a < 14; a++) {
        bx[a] = s[3 * a]; by[a] = s[3 * a + 1]; bz[a] = s[3 * a + 2];
      }
    }

    // masks: 14 ints per residue, 8B-aligned -> int2 x7 (both halves read, cached)
    const int2* mp2 = (const int2*)(sc_mask + (size_t)sb * 1792 + r * 14);
    float m[14];
#pragma unroll
    for (int k = 0; k < 7; k++) {
      int2 v = mp2[k];
      m[2 * k] = (v.x != 0) ? 1.f : 0.f;
      m[2 * k + 1] = (v.y != 0) ? 1.f : 0.f;
    }

    float mse = 0.f, am = 0.f;
    if (half == 0) {  // wave-uniform: half 1 never contributes mse/am
#pragma unroll
      for (int a = 0; a < 14; a++) {
        float dx = ax[a] - bx[a], dy = ay[a] - by[a], dz = az[a] - bz[a];
        mse += m[a] * ((dx * dx + dy * dy + dz * dz) * (1.f / 3.f));
        am += m[a];
      }
    }
#pragma unroll
    for (int a = 0; a < 14; a++) {
      // fold mask into tgt coords: masked atoms pushed far apart (distinct per
      // atom so masked-masked pairs are also far) -> td > CUTOFF -> w = 0
      bx[a] += (1.f - m[a]) * (30000.f * (float)(a + 1));
    }

    // triangular pair sum; reference's ordered sum = 2x this (diag has tsq==0)
    float num = 0.f, den = 0.f;
    if (half == 0) {
#pragma unroll
      for (int j = 1; j <= 9; j++) {
#pragma unroll
        for (int i = 0; i < j; i++) {
          float dx = bx[i] - bx[j], dy = by[i] - by[j], dz = bz[i] - bz[j];
          float td = FSQRT(dx * dx + dy * dy + dz * dz);
          float w = (td <= CUTOFF) ? 1.f : 0.f;
          float qx = ax[i] - ax[j], qy = ay[i] - ay[j], qz = az[i] - az[j];
          float pd = FSQRT(qx * qx + qy * qy + qz * qz);
          float d = pd - td;
          num += (w * d) * d;
          den += w;
        }
      }
    } else {
#pragma unroll
      for (int j = 10; j <= 13; j++) {
#pragma unroll
        for (int i = 0; i < j; i++) {
          float dx = bx[i] - bx[j], dy = by[i] - by[j], dz = bz[i] - bz[j];
          float td = FSQRT(dx * dx + dy * dy + dz * dz);
          float w = (td <= CUTOFF) ? 1.f : 0.f;
          float qx = ax[i] - ax[j], qy = ay[i] - ay[j], qz = az[i] - az[j];
          float pd = FSQRT(qx * qx + qy * qy + qz * qz);
          float d = pd - td;
          num += (w * d) * d;
          den += w;
        }
      }
    }

    // combine halves per residue, then nonlinear group step (half 0 owns it)
    if (half == 1) scpart[r] = make_float2(num, den);
    __syncthreads();
    float val = 0.f, has = 0.f;
    if (half == 0) {
      float2 o = scpart[r];
      float ng = num + o.x, dg = den + o.y;
      val = (dg > 0.f) ? (ng + ng) / fmaxf(dg + dg, 1.f) : 0.f;
      has = (dg > 0.f) ? 1.f : 0.f;
    }

    for (int off = 32; off > 0; off >>= 1) {
      mse += __shfl_down(mse, off, 64);
      am += __shfl_down(am, off, 64);
      val += __shfl_down(val, off, 64);
      has += __shfl_down(has, off, 64);
    }
    int lane = tid & 63, wv = tid >> 6;
    if (lane == 0) { red[0][wv] = mse; red[1][wv] = am; red[2][wv] = val; red[3][wv] = has; }
    __syncthreads();
    if (tid == 0) {
      float* p = ws + 1088 + (size_t)sb * 4;
      p[0] = red[0][0] + red[0][1] + red[0][2] + red[0][3];
      p[1] = red[1][0] + red[1][1] + red[1][2] + red[1][3];
      p[2] = red[2][0] + red[2][1] + red[2][2] + red[2][3];
      p[3] = red[3][0] + red[3][1] + red[3][2] + red[3][3];
    }
  } else {
    // ====== ligand: triangular, balanced tile-pairs {t,15-t}, 3 fused j-slots ======
    // Slot A0: j = i0a+tid          (always valid; gate j>i <=> tid>ii)
    // Slot A1: j = i0a+256+tid      (valid iff j<512; triangular gate always true)
    // Slot B : j = i0b+tid          (valid iff j<512; gate tid>ii)
    // Same covered pair set as R7 (verified); invalid slots predicated w=0.
    const int L = 512;
    const int lb = blockIdx.x - NSC_BLK;  // 0..511
    const int b = lb >> 3;
    const int t = lb & 7;
    const int i0a = 32 * t;
    const int i0b = 32 * (15 - t);
    const float* pb = lig_pred + (size_t)b * L * 3;
    const float* tb = lig_tgt + (size_t)b * L * 3;
    const int* mb = lig_mask + (size_t)b * L;

    float4* st4 = stage4;       // [0,32): tileA tgt(+mask), [32,64): tileB tgt(+mask)
    float4* sp4 = stage4 + 64;  // [0,32): tileA pred,       [32,64): tileB pred

    if (tid < 128) {
      int which = tid >> 5;  // 0: A-tgt, 1: B-tgt, 2: A-pred, 3: B-pred
      int idx = tid & 31;
      int i = ((which & 1) ? i0b : i0a) + idx;
      if (which < 2) {
        st4[(which << 5) + idx] =
            make_float4(tb[3 * i], tb[3 * i + 1], tb[3 * i + 2], (mb[i] != 0) ? 1.f : 0.f);
      } else {
        sp4[((which & 1) << 5) + idx] =
            make_float4(pb[3 * i], pb[3 * i + 1], pb[3 * i + 2], 0.f);
      }
    }

    // j-point loads (overlap with staging; barrier below covers both)
    const int jA0 = i0a + tid;
    const int jA1r = i0a + 256 + tid;
    const int jA1 = jA1r & (L - 1);  // clamp into bounds; weight zeroed if invalid
    const int jBr = i0b + tid;
    const int jB = jBr & (L - 1);

    float pA0x = pb[3 * jA0], pA0y = pb[3 * jA0 + 1], pA0z = pb[3 * jA0 + 2];
    float tA0x = tb[3 * jA0], tA0y = tb[3 * jA0 + 1], tA0z = tb[3 * jA0 + 2];
    float mA0 = (mb[jA0] != 0) ? 1.f : 0.f;
    float pA1x = pb[3 * jA1], pA1y = pb[3 * jA1 + 1], pA1z = pb[3 * jA1 + 2];
    float tA1x = tb[3 * jA1], tA1y = tb[3 * jA1 + 1], tA1z = tb[3 * jA1 + 2];
    float mA1 = (jA1r < L && mb[jA1] != 0) ? 1.f : 0.f;
    float pBx = pb[3 * jB], pBy = pb[3 * jB + 1], pBz = pb[3 * jB + 2];
    float tBx = tb[3 * jB], tBy = tb[3 * jB + 1], tBz = tb[3 * jB + 2];
    float mB = (jBr < L && mb[jB] != 0) ? 1.f : 0.f;

    float se = 0.f, cnt = 0.f;
    if (t == 0) {  // A0 (j=tid) + A1 (j=256+tid, all valid at t==0) cover all 512 atoms
      float dx = pA0x - tA0x, dy = pA0y - tA0y, dz = pA0z - tA0z;
      se += mA0 * (dx * dx + dy * dy + dz * dz);
      cnt += mA0;
      dx = pA1x - tA1x; dy = pA1y - tA1y; dz = pA1z - tA1z;
      se += mA1 * (dx * dx + dy * dy + dz * dz);
      cnt += mA1;
    }
    __syncthreads();

    // num,den accumulate exactly HALF of the reference's symmetric sums.
    float nA0 = 0.f, dA0 = 0.f, nA1 = 0.f, dA1 = 0.f, nB = 0.f, dB = 0.f;
#pragma unroll 8
    for (int ii = 0; ii < 32; ii++) {
      float4 tiA = st4[ii];  // wave-uniform -> broadcast ds_read_b128
      float4 piA = sp4[ii];
      float4 tiB = st4[32 + ii];
      float4 piB = sp4[32 + ii];
      float wA0 = (tid > ii) ? tiA.w * mA0 : 0.f;
      PAIR_EVAL(tiA, piA, tA0x, tA0y, tA0z, pA0x, pA0y, pA0z, wA0, nA0, dA0);
      float wA1 = tiA.w * mA1;  // triangular gate provably true for this slot
      PAIR_EVAL(tiA, piA, tA1x, tA1y, tA1z, pA1x, pA1y, pA1z, wA1, nA1, dA1);
      float wB = (tid > ii) ? tiB.w * mB : 0.f;
      PAIR_EVAL(tiB, piB, tBx, tBy, tBz, pBx, pBy, pBz, wB, nB, dB);
    }

    float num = nA0 + nA1 + nB, den = dA0 + dA1 + dB;
    for (int off = 32; off > 0; off >>= 1) {
      num += __shfl_down(num, off, 64);
      den += __shfl_down(den, off, 64);
      se += __shfl_down(se, off, 64);
      cnt += __shfl_down(cnt, off, 64);
    }
    int lane = tid & 63, wv = tid >> 6;
    if (lane == 0) { red[0][wv] = num; red[1][wv] = den; red[2][wv] = se; red[3][wv] = cnt; }
    __syncthreads();
    if (tid == 0) {
      ws[lb * 2 + 0] = red[0][0] + red[0][1] + red[0][2] + red[0][3];
      ws[lb * 2 + 1] = red[1][0] + red[1][1] + red[1][2] + red[1][3];
      if (t == 0) {
        float se_t = red[2][0] + red[2][1] + red[2][2] + red[2][3];
        float cnt_t = red[3][0] + red[3][1] + red[3][2] + red[3][3];
        ws[1024 + b] = se_t / (3.f * fmaxf(cnt_t, 1.f));
      }
    }
  }
}

__global__ __launch_bounds__(256) void finalize_kernel(const float* __restrict__ ws,
                                                       float* __restrict__ out) {
  const int tid = threadIdx.x;
  __shared__ float sred[4][4];

  const float* sc = ws + 1088;
  float s0 = 0.f, s1 = 0.f, s2 = 0.f, s3 = 0.f;
  for (int i = tid; i < 512; i += 256) {
    s0 += sc[4 * i + 0]; s1 += sc[4 * i + 1]; s2 += sc[4 * i + 2]; s3 += sc[4 * i + 3];
  }
  for (int off = 32; off > 0; off >>= 1) {
    s0 += __shfl_down(s0, off, 64);
    s1 += __shfl_down(s1, off, 64);
    s2 += __shfl_down(s2, off, 64);
    s3 += __shfl_down(s3, off, 64);
  }
  int lane = tid & 63, wv = tid >> 6;
  if (lane == 0) { sred[0][wv] = s0; sred[1][wv] = s1; sred[2][wv] = s2; sred[3][wv] = s3; }
  __syncthreads();

  float lval = 0.f, lhas = 0.f, lcoord = 0.f;
  if (tid < 64) {
    float n = 0.f, d = 0.f;
    for (int t = 0; t < 8; t++) {
      n += ws[(tid * 8 + t) * 2 + 0];
      d += ws[(tid * 8 + t) * 2 + 1];
    }
    lval = (d > 0.f) ? n / fmaxf(d, 1.f) : 0.f;
    lhas = (d > 0.f) ? 1.f : 0.f;
    lcoord = ws[1024 + tid];
    for (int off = 32; off > 0; off >>= 1) {
      lval += __shfl_down(lval, off, 64);
      lhas += __shfl_down(lhas, off, 64);
      lcoord += __shfl_down(lcoord, off, 64);
    }
  }
  if (tid == 0) {
    float sc_mse = sred[0][0] + sred[0][1] + sred[0][2] + sred[0][3];
    float sc_am = sred[1][0] + sred[1][1] + sred[1][2] + sred[1][3];
    float sc_val = sred[2][0] + sred[2][1] + sred[2][2] + sred[2][3];
    float sc_has = sred[3][0] + sred[3][1] + sred[3][2] + sred[3][3];
    float ligand_loss = lcoord * (1.f / 64.f);
    float ligand_dist_loss = lval / fmaxf(lhas, 1.f);
    float sidechain_loss = sc_mse / fmaxf(sc_am, 1.f);
    float sidechain_dist_loss = sc_val / fmaxf(sc_has, 1.f);
    out[0] = ligand_loss + 0.2f * ligand_dist_loss + 0.5f * sidechain_loss +
             0.1f * sidechain_dist_loss;
  }
}

extern "C" void kernel_launch(void* const* d_in, const int* in_sizes, int n_in,
                              void* d_out, int out_size, void* d_ws, size_t ws_size,
                              hipStream_t stream) {
  const float* ligand_pred = (const float*)d_in[0];
  const float* ligand_tgt = (const float*)d_in[1];
  const float* sidechain_pred = (const float*)d_in[2];
  const float* sidechain_tgt = (const float*)d_in[3];
  const int* ligand_mask = (const int*)d_in[4];
  const int* atom_mask = (const int*)d_in[5];
  float* out = (float*)d_out;
  float* ws = (float*)d_ws;

  fused_kernel<<<GRID, 256, 0, stream>>>(ligand_pred, ligand_tgt, ligand_mask,
                                         sidechain_pred, sidechain_tgt, atom_mask, ws);
  finalize_kernel<<<1, 256, 0, stream>>>(ws, out);
}